// Round 18
// baseline (238.446 us; speedup 1.0000x reference)
//
#include <hip/hip_runtime.h>

// out[b,n] = sum_{c,hw} x[b,c,hw] * W_s[n,hw] * W_d[n,c] + W_b[n]
// B=512, C=384, N=512, HW=169 (13x13).
//
// R25 = R24 + EXPLICIT vmcnt(0) drain before every barrier in conv_part.
// R24 post-mortem: pre-timing PASSED, post-timing diverged (absmax 139.5) =
// intermittent race. All indexing/coverage re-audited clean; the one
// timing-dependent mechanism is the global_load_lds DMA drain at barriers:
// correctness needs s_waitcnt vmcnt(0) before s_barrier so the staged
// buffer is complete before other waves' ds_reads. We relied on the
// compiler emitting it (m97); R24's changed schedule ((256,3), 2x compute
// per chunk) may have lost it — the staging ops have no in-kernel consumer
// the compiler can see. Fix: asm volatile("s_waitcnt vmcnt(0)") before
// every __syncthreads. Zero cost if redundant.
// Everything else = R24: b-pair (one B-read feeds 4 MFMA), 16 chunks x 2 nf,
// 12KB dbuf staged by global_load_lds(16B), wdf preloaded BEFORE staging,
// shfl+red epilogue per b, 3-slab part + reducer, XCD swizzle.
// Detectors: WRITE ~3MB; if post-timing diverges AGAIN -> revert to R23.

#define B_   512
#define C_   384
#define N_   512
#define HW_  169
#define CT   128     // c-tile rows (3 c_blks per b)
#define SXR  200     // Xs row stride (v8/fallback kernels)

#define WSF_ELEMS  ((size_t)32 * 6 * 64 * 8)       // 98,304 bf16 (192 KB)
#define WDF_ELEMS  ((size_t)24 * 32 * 64 * 4)      // 196,608 f32 (768 KB)
#define PART_ELEMS ((size_t)3 * B_ * N_)           // 786,432 f32 (3 MB)

typedef __bf16 bf16x8 __attribute__((ext_vector_type(8)));
typedef float f32x4  __attribute__((ext_vector_type(4)));
typedef float f32x4u __attribute__((ext_vector_type(4), aligned(4)));
typedef unsigned u32x4 __attribute__((ext_vector_type(4)));

__device__ __forceinline__ __bf16 f2bf(float f) {
  union { float f; unsigned u; } v; v.f = f;
  unsigned r = (v.u + 0x7FFFu + ((v.u >> 16) & 1u)) >> 16;   // RNE
  unsigned short s = (unsigned short)r;
  return __builtin_bit_cast(__bf16, s);
}

// hi16(a)|hi16(b)<<16 : two bf16 truncations in one v_perm
__device__ __forceinline__ unsigned pack_trunc(float a, float b) {
  return __builtin_amdgcn_perm(__builtin_bit_cast(unsigned, b),
                               __builtin_bit_cast(unsigned, a), 0x07060302u);
}

// async global->LDS, 16B per lane (wave-uniform LDS base + lane*16)
__device__ __forceinline__ void gload_lds16(const __bf16* g, __bf16* l) {
  __builtin_amdgcn_global_load_lds(
      (const __attribute__((address_space(1))) unsigned*)(g),
      (__attribute__((address_space(3))) unsigned*)(l),
      16, 0, 0);
}

// explicit DMA drain: the staging queue MUST be complete before s_barrier
__device__ __forceinline__ void drain_vmem() {
  asm volatile("s_waitcnt vmcnt(0)" ::: "memory");
}

// ---------------- prep_aux: wsf (B-frag order) + wdf (C-layout order) ----------------
__global__ __launch_bounds__(256)
void prep_aux_kernel(const float* __restrict__ Ws,
                     const float* __restrict__ Wd,
                     __bf16* __restrict__ wsf,
                     float* __restrict__ wdf) {
  int t = blockIdx.x * 256 + threadIdx.x;      // 61440 total, exact
  if (t < 12288) {
    // wsf: t = (nm*6 + kb)*64 + lane ; lane(q=l>>4,m=l&15) holds Ws[nm*16+m][kb*32+q*8+j]
    int lane = t & 63;
    int fr   = t >> 6;
    int kb   = fr % 6;
    int nm   = fr / 6;
    int n    = nm * 16 + (lane & 15);
    int k0   = kb * 32 + (lane >> 4) * 8;
    const float* src = Ws + (size_t)n * HW_;
    bf16x8 v;
    #pragma unroll
    for (int j = 0; j < 8; ++j) {
      int k = k0 + j;
      float f = (k < HW_) ? src[k] : 0.f;
      v[j] = f2bf(f);
    }
    *(bf16x8*)(wsf + (size_t)t * 8) = v;
  } else {
    // wdf: t2 = (cm*32 + nm)*64 + lane; elem i = Wd[nm*16+(l&15)][cm*16+(l>>4)*4+i]
    int t2 = t - 12288;
    int lane = t2 & 63;
    int fr   = t2 >> 6;
    int nm   = fr & 31;
    int cm   = fr >> 5;
    int n    = nm * 16 + (lane & 15);
    int c0   = cm * 16 + (lane >> 4) * 4;
    f32x4 w = *(const f32x4u*)(Wd + (size_t)n * C_ + c0);
    *(f32x4*)(wdf + (size_t)t2 * 4) = w;
  }
}

// ---------------- R25 main kernel: b-pair, LDS-B pipelined, explicit drains ----------------
__global__ __launch_bounds__(256, 3)       // ~160 regs -> 170-band
void conv_part(const float* __restrict__ x,
               const __bf16* __restrict__ wsf,
               const float* __restrict__ wdf,
               float* __restrict__ part) {
  __shared__ __align__(16) __bf16 Bs[2][12 * 512];  // 2 x 12KB double buffer
  __shared__ float red[2][4 * 512];                 // 16 KB -> 40KB total

  const int tid  = threadIdx.x;
  // XCD swizzle: the 3 c_blks of one b-pair land on the same id%8 slot.
  const int id    = blockIdx.x;     // 0..767
  const int slot  = id & 7;
  const int t8    = id >> 3;        // 0..95
  const int c_blk = t8 % 3;
  const int bp    = (t8 / 3) * 8 + slot;    // b-pair 0..255
  const int b0    = bp * 2;

  const int lane  = tid & 63;
  const int wv    = tid >> 6;          // 4 waves; wave owns 32 c-rows x 2 b
  const int lrow  = lane & 15;
  const int lquad = lane >> 4;

  // ---- A-fragments DIRECT from global for BOTH batches: 24 frags ----
  bf16x8 a[2][2][6];                   // [bi][mi][kb]
  #pragma unroll
  for (int bi = 0; bi < 2; ++bi) {
    #pragma unroll
    for (int mi = 0; mi < 2; ++mi) {
      const float* rp = x + ((size_t)(b0 + bi) * C_ + (size_t)c_blk * CT
                             + wv * 32 + mi * 16 + lrow) * HW_;
      #pragma unroll
      for (int kb = 0; kb < 6; ++kb) {
        const int k0 = kb * 32 + lquad * 8;
        float v0, v1, v2, v3, v4, v5, v6, v7;
        if (kb < 5 || k0 + 7 < HW_) {          // kb<=4 always safe (max 159)
          f32x4u t0 = *(const f32x4u*)(rp + k0);
          f32x4u t1 = *(const f32x4u*)(rp + k0 + 4);
          v0 = t0[0]; v1 = t0[1]; v2 = t0[2]; v3 = t0[3];
          v4 = t1[0]; v5 = t1[1]; v6 = t1[2]; v7 = t1[3];
        } else {                               // kb==5 tail: col 168 then pad
          v0 = (k0 + 0 < HW_) ? rp[k0 + 0] : 0.f;
          v1 = v2 = v3 = v4 = v5 = v6 = v7 = 0.f;
        }
        u32x4 pk;
        pk.x = pack_trunc(v0, v1);
        pk.y = pack_trunc(v2, v3);
        pk.z = pack_trunc(v4, v5);
        pk.w = pack_trunc(v6, v7);
        a[bi][mi][kb] = __builtin_bit_cast(bf16x8, pk);
      }
    }
  }

  const int cm0 = c_blk * 8 + wv * 2;       // global 16-c fragment row (0..23)
  const float* wb = wdf + (size_t)lane * 4;
  const f32x4 zero = {0.f, 0.f, 0.f, 0.f};

  // ---- prologue: stage chunk 0 (12 x 1KB fragments; 3 per wave) ----
  {
    const __bf16* g = wsf + ((size_t)(wv * 3) * 512) + (size_t)lane * 8;
    __bf16* l = &Bs[0][(wv * 3) * 512];
    #pragma unroll
    for (int j = 0; j < 3; ++j)
      gload_lds16(g + j * 512, l + j * 512);
  }
  drain_vmem();      // DMA for chunk 0 complete before barrier
  __syncthreads();

  // ---- 16 chunks x 2 nf: one B-read feeds 4 MFMA (2 b x 2 mi) ----
  #pragma unroll 1
  for (int ch = 0; ch < 16; ++ch) {
    const int buf = ch & 1;

    // (1) wdf preload for THIS chunk (shared across bi) — issued FIRST so
    //     the fold's counted vmcnt doesn't drain the staging queue below.
    f32x4 w[2][2];
    #pragma unroll
    for (int nfi = 0; nfi < 2; ++nfi)
      #pragma unroll
      for (int mi = 0; mi < 2; ++mi)
        w[nfi][mi] = *(const f32x4*)(wb +
            (((size_t)(cm0 + mi) * 32 + (ch * 2 + nfi)) * 256));

    // (2) stage NEXT chunk into the other buffer (no wait)
    if (ch < 15) {
      const __bf16* g = wsf + ((size_t)((ch + 1) * 12 + wv * 3) * 512) + (size_t)lane * 8;
      __bf16* l = &Bs[buf ^ 1][(wv * 3) * 512];
      #pragma unroll
      for (int j = 0; j < 3; ++j)
        gload_lds16(g + j * 512, l + j * 512);
    }

    // (3) compute 2 nf; bfr live one at a time, feeding 4 MFMA
    #pragma unroll
    for (int nfi = 0; nfi < 2; ++nfi) {
      f32x4 acc[2][2] = {{zero, zero}, {zero, zero}};
      #pragma unroll
      for (int kb = 0; kb < 6; ++kb) {
        const bf16x8 bfr = *(const bf16x8*)&Bs[buf][(nfi * 6 + kb) * 512 + lane * 8];
        #pragma unroll
        for (int bi = 0; bi < 2; ++bi) {
          acc[bi][0] = __builtin_amdgcn_mfma_f32_16x16x32_bf16(a[bi][0][kb], bfr, acc[bi][0], 0, 0, 0);
          acc[bi][1] = __builtin_amdgcn_mfma_f32_16x16x32_bf16(a[bi][1][kb], bfr, acc[bi][1], 0, 0, 0);
        }
      }

      #pragma unroll
      for (int bi = 0; bi < 2; ++bi) {
        float t = 0.f;
        #pragma unroll
        for (int mi = 0; mi < 2; ++mi)
          t += acc[bi][mi][0] * w[nfi][mi][0] + acc[bi][mi][1] * w[nfi][mi][1]
             + acc[bi][mi][2] * w[nfi][mi][2] + acc[bi][mi][3] * w[nfi][mi][3];
        // lanes {m,m+16,m+32,m+48} hold disjoint c-slices of the same n
        t += __shfl_xor(t, 16, 64);
        t += __shfl_xor(t, 32, 64);
        if (lane < 16)
          red[bi][wv * 512 + (ch * 2 + nfi) * 16 + lrow] = t;
      }
    }

    drain_vmem();    // staging(ch+1) DMA complete before barrier
    __syncthreads(); // fences buf reuse + red visibility
  }

  // ---- combine: 256 threads x 2 n x 2 b -> complete partials, plain store ----
  float* pb = part + ((size_t)c_blk * B_ + b0) * N_;
  #pragma unroll
  for (int r = 0; r < 2; ++r) {
    const int n = r * 256 + tid;
    #pragma unroll
    for (int bi = 0; bi < 2; ++bi) {
      const float* rb = red[bi];
      float v = rb[n] + rb[512 + n] + rb[1024 + n] + rb[1536 + n];
      pb[(size_t)bi * N_ + n] = v;
    }
  }
}

// ---------------- reducer: out = sum of 3 slabs + bias ----------------
__global__ __launch_bounds__(256)
void reduce_part(const float* __restrict__ part,
                 const float* __restrict__ Wb,
                 float* __restrict__ out) {
  const size_t S = (size_t)B_ * N_;
  int idx = (blockIdx.x * 256 + threadIdx.x) * 4;   // 256 blocks -> covers 262144
  f32x4 a0 = *(const f32x4u*)(part + idx);
  f32x4 a1 = *(const f32x4u*)(part + S + idx);
  f32x4 a2 = *(const f32x4u*)(part + 2 * S + idx);
  f32x4 wb = *(const f32x4u*)(Wb + (idx & (N_ - 1)));
  f32x4 r;
  #pragma unroll
  for (int i = 0; i < 4; ++i)
    r[i] = a0[i] + a1[i] + a2[i] + wb[i];
  *(f32x4*)(out + idx) = r;
}

// ---------------- R8 main kernel (ws fits wsf+wdf only; 110 us proven) ----------------
__global__ __launch_bounds__(256, 3)
void conv_fused_v8(const float* __restrict__ x,
                   const __bf16* __restrict__ wsf,
                   const float* __restrict__ wdf,
                   const float* __restrict__ Wb,
                   float* __restrict__ out) {
  __shared__ __align__(16) __bf16 Xs[CT * SXR];   // 51.2 KB
  __shared__ float red[4][64];                     // 1 KB

  const int tid  = threadIdx.x;
  const int id    = blockIdx.x;     // 0..1535
  const int slot  = id & 7;
  const int t8    = id >> 3;        // 0..191
  const int c_blk = t8 % 3;
  const int b     = (t8 / 3) * 8 + slot;

  const int lane  = tid & 63;
  const int wv    = tid >> 6;          // 4 waves: 2x2 (c,n) 64x64 quadrants
  const int cq    = (wv >> 1) * 64;
  const int nq    = (wv & 1) * 64;
  const int lrow  = lane & 15;
  const int lquad = lane >> 4;

  const float* src = x + ((size_t)b * C_ + (size_t)c_blk * CT) * HW_;
  #pragma unroll 4
  for (int p = 0; p < 24; ++p) {
    int i   = p * 256 + tid;
    int row = i / 48;
    int ch  = i - row * 48;
    const float* bp = src + row * HW_ + ch * 4;
    float v0 = 0.f, v1 = 0.f, v2 = 0.f, v3 = 0.f;
    if (ch < 42) {
      f32x4u t = *(const f32x4u*)bp;
      v0 = t[0]; v1 = t[1]; v2 = t[2]; v3 = t[3];
    } else if (ch == 42) {
      v0 = bp[0];
    }
    unsigned d0 = pack_trunc(v0, v1);
    unsigned d1 = pack_trunc(v2, v3);
    uint2 d; d.x = d0; d.y = d1;
    *(uint2*)&Xs[row * SXR + ch * 4] = d;
  }
  __syncthreads();

  const int cm0 = c_blk * 8 + (cq >> 4);

  #pragma unroll 1
  for (int nb = 0; nb < 4; ++nb) {
    const int nm0 = nb * 8 + (nq >> 4);
    const __bf16* bbase = wsf + ((size_t)nm0 * 6) * 512 + (size_t)lane * 8;

    const f32x4 zero = {0.f, 0.f, 0.f, 0.f};
    f32x4 acc[4][4];
    #pragma unroll
    for (int mi = 0; mi < 4; ++mi)
      #pragma unroll
      for (int ni = 0; ni < 4; ++ni)
        acc[mi][ni] = zero;

    #pragma unroll
    for (int kb = 0; kb < 6; ++kb) {
      bf16x8 afr[4], bfr[4];
      #pragma unroll
      for (int mi = 0; mi < 4; ++mi)
        afr[mi] = *(const bf16x8*)&Xs[(cq + mi * 16 + lrow) * SXR + kb * 32 + lquad * 8];
      #pragma unroll
      for (int ni = 0; ni < 4; ++ni)
        bfr[ni] = *(const bf16x8*)(bbase + ((size_t)ni * 6 + kb) * 512);
      #pragma unroll
      for (int mi = 0; mi < 4; ++mi)
        #pragma unroll
        for (int ni = 0; ni < 4; ++ni)
          acc[mi][ni] = __builtin_amdgcn_mfma_f32_16x16x32_bf16(
              afr[mi], bfr[ni], acc[mi][ni], 0, 0, 0);
    }

    float s[4] = {0.f, 0.f, 0.f, 0.f};
    #pragma unroll
    for (int ni = 0; ni < 4; ++ni) {
      #pragma unroll
      for (int mi = 0; mi < 4; ++mi) {
        const f32x4 w = *(const f32x4*)(wdf +
            (((size_t)(cm0 + mi) * 32 + (nm0 + ni)) * 64 + lane) * 4);
        s[ni] += acc[mi][ni][0] * w[0] + acc[mi][ni][1] * w[1]
               + acc[mi][ni][2] * w[2] + acc[mi][ni][3] * w[3];
      }
    }

    #pragma unroll
    for (int ni = 0; ni < 4; ++ni) {
      s[ni] += __shfl_xor(s[ni], 16, 64);
      s[ni] += __shfl_xor(s[ni], 32, 64);
    }
    if (lane < 16) {
      #pragma unroll
      for (int ni = 0; ni < 4; ++ni)
        red[wv][ni * 16 + lrow] = s[ni];
    }
    __syncthreads();

    if (tid < 128) {
      const int half = tid >> 6;
      const int idx  = tid & 63;
      const int n    = nb * 128 + tid;
      float v = red[half][idx] + red[half + 2][idx];
      if (c_blk == 0) v += Wb[n];
      atomicAdd(&out[(size_t)b * N_ + n], v);
    }
    __syncthreads();
  }
}

// ---------------- fallback main kernel (no workspace needed) ----------------

#define LDSS 104
#define KCH  96
#define NT   128

__global__ __launch_bounds__(256)
void conv_main_fallback(const float* __restrict__ x,
                        const float* __restrict__ Ws_g,
                        const float* __restrict__ Wd,
                        const float* __restrict__ Wb,
                        float* __restrict__ out) {
  __shared__ __align__(16) __bf16 Xs[CT][LDSS];
  __shared__ __align__(16) __bf16 Ws[NT][LDSS];

  const int tid   = threadIdx.x;
  const int n_blk = blockIdx.x;
  const int c_blk = blockIdx.y;
  const int b     = blockIdx.z;
  const int c0 = c_blk * CT;
  const int n0 = n_blk * NT;
  const int lane  = tid & 63;
  const int wv    = tid >> 6;
  const int cq    = (wv >> 1) * 64;
  const int nq    = (wv & 1) * 64;
  const int lrow  = lane & 15;
  const int lquad = lane >> 4;

  const f32x4 zero = {0.f, 0.f, 0.f, 0.f};
  f32x4 acc[4][4];
  #pragma unroll
  for (int mi = 0; mi < 4; ++mi)
    #pragma unroll
    for (int ni = 0; ni < 4; ++ni)
      acc[mi][ni] = zero;

  const float* xb  = x    + (size_t)b  * (C_ * HW_) + (size_t)c0 * HW_;
  const float* wsb = Ws_g + (size_t)n0 * HW_;

  for (int ch = 0; ch < 2; ++ch) {
    const int k0 = ch * KCH;
    __syncthreads();
    for (int e = tid; e < CT * KCH; e += 256) {
      int r   = e / KCH;
      int col = e - r * KCH;
      int k   = k0 + col;
      float vx = 0.f, vw = 0.f;
      if (k < HW_) {
        vx = xb [r * HW_ + k];
        vw = wsb[r * HW_ + k];
      }
      Xs[r][col] = f2bf(vx);
      Ws[r][col] = f2bf(vw);
    }
    __syncthreads();

    #pragma unroll
    for (int ks = 0; ks < 3; ++ks) {
      const int kc = ks * 32 + lquad * 8;
      bf16x8 afr[4], bfr[4];
      #pragma unroll
      for (int mi = 0; mi < 4; ++mi)
        afr[mi] = *(const bf16x8*)&Xs[cq + mi * 16 + lrow][kc];
      #pragma unroll
      for (int ni = 0; ni < 4; ++ni)
        bfr[ni] = *(const bf16x8*)&Ws[nq + ni * 16 + lrow][kc];
      #pragma unroll
      for (int mi = 0; mi < 4; ++mi)
        #pragma unroll
        for (int ni = 0; ni < 4; ++ni)
          acc[mi][ni] = __builtin_amdgcn_mfma_f32_16x16x32_bf16(
              afr[mi], bfr[ni], acc[mi][ni], 0, 0, 0);
    }
  }

  #pragma unroll
  for (int ni = 0; ni < 4; ++ni) {
    const int n = n0 + nq + ni * 16 + lrow;
    float sv = 0.f;
    #pragma unroll
    for (int mi = 0; mi < 4; ++mi) {
      const int cbase = c0 + cq + mi * 16 + lquad * 4;
      #pragma unroll
      for (int i = 0; i < 4; ++i)
        sv += acc[mi][ni][i] * Wd[(size_t)n * C_ + (cbase + i)];
    }
    sv += __shfl_xor(sv, 16, 64);
    sv += __shfl_xor(sv, 32, 64);
    if (lane < 16) {
      if (c_blk == 0 && cq == 0) sv += Wb[n];
      atomicAdd(&out[(size_t)b * N_ + n], sv);
    }
  }
}

extern "C" void kernel_launch(void* const* d_in, const int* in_sizes, int n_in,
                              void* d_out, int out_size, void* d_ws, size_t ws_size,
                              hipStream_t stream) {
  const float* x   = (const float*)d_in[0];   // [512,384,13,13]
  const float* Wsp = (const float*)d_in[1];   // [512,13,13]
  const float* Wd  = (const float*)d_in[2];   // [512,384]
  const float* Wb  = (const float*)d_in[3];   // [1,512]
  float* out = (float*)d_out;                 // [512,512] fp32

  const size_t need_basic = WSF_ELEMS * sizeof(__bf16) + WDF_ELEMS * sizeof(float);
  const size_t need_full  = need_basic + PART_ELEMS * sizeof(float);

  if (ws_size >= need_full) {
    __bf16* wsf  = (__bf16*)d_ws;
    float*  wdf  = (float*)(wsf + WSF_ELEMS);
    float*  partb = wdf + WDF_ELEMS;

    prep_aux_kernel<<<240, 256, 0, stream>>>(Wsp, Wd, wsf, wdf);
    conv_part<<<768, 256, 0, stream>>>(x, wsf, wdf, partb);
    reduce_part<<<256, 256, 0, stream>>>(partb, Wb, out);
  } else if (ws_size >= need_basic) {
    __bf16* wsf = (__bf16*)d_ws;
    float*  wdf = (float*)(wsf + WSF_ELEMS);

    hipMemsetAsync(d_out, 0, (size_t)out_size * sizeof(float), stream);
    prep_aux_kernel<<<240, 256, 0, stream>>>(Wsp, Wd, wsf, wdf);
    conv_fused_v8<<<1536, 256, 0, stream>>>(x, wsf, wdf, Wb, out);
  } else {
    hipMemsetAsync(d_out, 0, (size_t)out_size * sizeof(float), stream);
    dim3 grid(N_ / NT, C_ / CT, B_);
    conv_main_fallback<<<grid, 256, 0, stream>>>(x, Wsp, Wd, Wb, out);
  }
}

// Round 19
// 225.863 us; speedup vs baseline: 1.0557x; 1.0557x over previous
//
#include <hip/hip_runtime.h>

// out[b,n] = sum_{c,hw} x[b,c,hw] * W_s[n,hw] * W_d[n,c] + W_b[n]
// B=512, C=384, N=512, HW=169 (13x13).
//
// R26 = REVERT to R23 (proven 83us conv_part / 225us total) + 2 safe tweaks.
// R24/R25 post-mortem: the b-pair structure spills at ANY register band
// (R25: WRITE 27.6MB, 98us at (256,3)) — a[2][2][6]=96 regs + temps > 170.
// Lane closed. R23 is the best verified structure:
//  - 16 chunks x 2 nf; wsf B-frags double-buffered in 2x12KB LDS staged by
//    global_load_lds(16B); one bfr live at a time feeds 2 MFMA; wdf
//    preloaded BEFORE staging; shfl+red epilogue; 3-slab part + reducer.
//  - launch_bounds(256,4): ~105-110 regs in the 128-band, 4 blocks/CU.
// Tweaks vs R23:
//  (1) explicit s_waitcnt vmcnt(0) before EVERY barrier (closes the
//      global_load_lds DMA-race class that bit R24; zero cost if the
//      compiler already emits it — R23 passed, so it did there).
//  (2) chunk-0 staging issued BEFORE the A-fragment loads: the 12KB DMA
//      completes underneath the ~48 long-latency A-loads + packing.
// Detectors: WRITE ~3MB, VGPR ~56, dur ~78-83us.

#define B_   512
#define C_   384
#define N_   512
#define HW_  169
#define CT   128     // c-tile rows (3 c_blks per b)
#define SXR  200     // Xs row stride (v8/fallback kernels)

#define WSF_ELEMS  ((size_t)32 * 6 * 64 * 8)       // 98,304 bf16 (192 KB)
#define WDF_ELEMS  ((size_t)24 * 32 * 64 * 4)      // 196,608 f32 (768 KB)
#define PART_ELEMS ((size_t)3 * B_ * N_)           // 786,432 f32 (3 MB)

typedef __bf16 bf16x8 __attribute__((ext_vector_type(8)));
typedef float f32x4  __attribute__((ext_vector_type(4)));
typedef float f32x4u __attribute__((ext_vector_type(4), aligned(4)));
typedef unsigned u32x4 __attribute__((ext_vector_type(4)));

__device__ __forceinline__ __bf16 f2bf(float f) {
  union { float f; unsigned u; } v; v.f = f;
  unsigned r = (v.u + 0x7FFFu + ((v.u >> 16) & 1u)) >> 16;   // RNE
  unsigned short s = (unsigned short)r;
  return __builtin_bit_cast(__bf16, s);
}

// hi16(a)|hi16(b)<<16 : two bf16 truncations in one v_perm
__device__ __forceinline__ unsigned pack_trunc(float a, float b) {
  return __builtin_amdgcn_perm(__builtin_bit_cast(unsigned, b),
                               __builtin_bit_cast(unsigned, a), 0x07060302u);
}

// async global->LDS, 16B per lane (wave-uniform LDS base + lane*16)
__device__ __forceinline__ void gload_lds16(const __bf16* g, __bf16* l) {
  __builtin_amdgcn_global_load_lds(
      (const __attribute__((address_space(1))) unsigned*)(g),
      (__attribute__((address_space(3))) unsigned*)(l),
      16, 0, 0);
}

// explicit DMA drain: the staging queue MUST be complete before s_barrier
__device__ __forceinline__ void drain_vmem() {
  asm volatile("s_waitcnt vmcnt(0)" ::: "memory");
}

// ---------------- prep_aux: wsf (B-frag order) + wdf (C-layout order) ----------------
__global__ __launch_bounds__(256)
void prep_aux_kernel(const float* __restrict__ Ws,
                     const float* __restrict__ Wd,
                     __bf16* __restrict__ wsf,
                     float* __restrict__ wdf) {
  int t = blockIdx.x * 256 + threadIdx.x;      // 61440 total, exact
  if (t < 12288) {
    // wsf: t = (nm*6 + kb)*64 + lane ; lane(q=l>>4,m=l&15) holds Ws[nm*16+m][kb*32+q*8+j]
    int lane = t & 63;
    int fr   = t >> 6;
    int kb   = fr % 6;
    int nm   = fr / 6;
    int n    = nm * 16 + (lane & 15);
    int k0   = kb * 32 + (lane >> 4) * 8;
    const float* src = Ws + (size_t)n * HW_;
    bf16x8 v;
    #pragma unroll
    for (int j = 0; j < 8; ++j) {
      int k = k0 + j;
      float f = (k < HW_) ? src[k] : 0.f;
      v[j] = f2bf(f);
    }
    *(bf16x8*)(wsf + (size_t)t * 8) = v;
  } else {
    // wdf: t2 = (cm*32 + nm)*64 + lane; elem i = Wd[nm*16+(l&15)][cm*16+(l>>4)*4+i]
    int t2 = t - 12288;
    int lane = t2 & 63;
    int fr   = t2 >> 6;
    int nm   = fr & 31;
    int cm   = fr >> 5;
    int n    = nm * 16 + (lane & 15);
    int c0   = cm * 16 + (lane >> 4) * 4;
    f32x4 w = *(const f32x4u*)(Wd + (size_t)n * C_ + c0);
    *(f32x4*)(wdf + (size_t)t2 * 4) = w;
  }
}

// ---------------- R26 main kernel: R23 + explicit drains + early staging ----------------
__global__ __launch_bounds__(256, 4)       // ~105-110 regs -> 128-band, 4 blocks/CU
void conv_part(const float* __restrict__ x,
               const __bf16* __restrict__ wsf,
               const float* __restrict__ wdf,
               float* __restrict__ part) {
  __shared__ __align__(16) __bf16 Bs[2][12 * 512];  // 2 x 12KB double buffer
  __shared__ float red[4 * 512];                    // 8 KB epilogue -> 32KB total

  const int tid  = threadIdx.x;
  // XCD swizzle: the 3 c_blks of one b land on the same id%8 slot.
  const int id    = blockIdx.x;     // 0..1535
  const int slot  = id & 7;
  const int t8    = id >> 3;        // 0..191
  const int c_blk = t8 % 3;
  const int b     = (t8 / 3) * 8 + slot;

  const int lane  = tid & 63;
  const int wv    = tid >> 6;          // 4 waves; wave owns 32 c-rows (2 frags)
  const int lrow  = lane & 15;
  const int lquad = lane >> 4;

  // ---- (2) chunk-0 staging issued FIRST: DMA runs under the A-loads ----
  {
    const __bf16* g = wsf + ((size_t)(wv * 3) * 512) + (size_t)lane * 8;
    __bf16* l = &Bs[0][(wv * 3) * 512];
    #pragma unroll
    for (int j = 0; j < 3; ++j)
      gload_lds16(g + j * 512, l + j * 512);
  }

  // ---- A-fragments DIRECT from global: 12 frags, f32x4 pairs, pack in-reg ----
  bf16x8 a[2][6];
  #pragma unroll
  for (int mi = 0; mi < 2; ++mi) {
    const float* rp = x + ((size_t)b * C_ + (size_t)c_blk * CT + wv * 32 + mi * 16 + lrow) * HW_;
    #pragma unroll
    for (int kb = 0; kb < 6; ++kb) {
      const int k0 = kb * 32 + lquad * 8;
      float v0, v1, v2, v3, v4, v5, v6, v7;
      if (kb < 5 || k0 + 7 < HW_) {          // kb<=4 always safe (max 159)
        f32x4u t0 = *(const f32x4u*)(rp + k0);
        f32x4u t1 = *(const f32x4u*)(rp + k0 + 4);
        v0 = t0[0]; v1 = t0[1]; v2 = t0[2]; v3 = t0[3];
        v4 = t1[0]; v5 = t1[1]; v6 = t1[2]; v7 = t1[3];
      } else {                               // kb==5 tail: col 168 then pad
        v0 = (k0 + 0 < HW_) ? rp[k0 + 0] : 0.f;
        v1 = v2 = v3 = v4 = v5 = v6 = v7 = 0.f;
      }
      u32x4 pk;
      pk.x = pack_trunc(v0, v1);
      pk.y = pack_trunc(v2, v3);
      pk.z = pack_trunc(v4, v5);
      pk.w = pack_trunc(v6, v7);
      a[mi][kb] = __builtin_bit_cast(bf16x8, pk);
    }
  }

  const int cm0 = c_blk * 8 + wv * 2;       // global 16-c fragment row (0..23)
  const float* wb = wdf + (size_t)lane * 4;
  const f32x4 zero = {0.f, 0.f, 0.f, 0.f};
  float* rbase = red + wv * 512;

  drain_vmem();      // (1) chunk-0 DMA (and A-loads) complete before barrier
  __syncthreads();

  // ---- 16 chunks x 2 nf: compute from LDS while staging next chunk ----
  #pragma unroll 1
  for (int ch = 0; ch < 16; ++ch) {
    const int buf = ch & 1;

    // wdf preload for THIS chunk — issued FIRST so the fold's counted
    // vmcnt doesn't drain the staging queue issued below.
    f32x4 w[2][2];
    #pragma unroll
    for (int nfi = 0; nfi < 2; ++nfi)
      #pragma unroll
      for (int mi = 0; mi < 2; ++mi)
        w[nfi][mi] = *(const f32x4*)(wb +
            (((size_t)(cm0 + mi) * 32 + (ch * 2 + nfi)) * 256));

    // stage NEXT chunk into the other buffer (no wait)
    if (ch < 15) {
      const __bf16* g = wsf + ((size_t)((ch + 1) * 12 + wv * 3) * 512) + (size_t)lane * 8;
      __bf16* l = &Bs[buf ^ 1][(wv * 3) * 512];
      #pragma unroll
      for (int j = 0; j < 3; ++j)
        gload_lds16(g + j * 512, l + j * 512);
    }

    // compute 2 nf from the current LDS buffer; bfr live one at a time
    #pragma unroll
    for (int nfi = 0; nfi < 2; ++nfi) {
      f32x4 acc[2] = {zero, zero};
      #pragma unroll
      for (int kb = 0; kb < 6; ++kb) {
        const bf16x8 bfr = *(const bf16x8*)&Bs[buf][(nfi * 6 + kb) * 512 + lane * 8];
        acc[0] = __builtin_amdgcn_mfma_f32_16x16x32_bf16(a[0][kb], bfr, acc[0], 0, 0, 0);
        acc[1] = __builtin_amdgcn_mfma_f32_16x16x32_bf16(a[1][kb], bfr, acc[1], 0, 0, 0);
      }

      float t = 0.f;
      #pragma unroll
      for (int mi = 0; mi < 2; ++mi)
        t += acc[mi][0] * w[nfi][mi][0] + acc[mi][1] * w[nfi][mi][1]
           + acc[mi][2] * w[nfi][mi][2] + acc[mi][3] * w[nfi][mi][3];
      // lanes {m,m+16,m+32,m+48} hold disjoint c-slices of the same n
      t += __shfl_xor(t, 16, 64);
      t += __shfl_xor(t, 32, 64);
      if (lane < 16)
        rbase[(ch * 2 + nfi) * 16 + lrow] = t;
    }

    drain_vmem();    // (1) staging(ch+1) DMA complete before barrier
    __syncthreads(); // fences buf reuse + red visibility
  }

  // ---- combine: 256 threads x 2 n -> complete partials, plain store ----
  float* pb = part + ((size_t)c_blk * B_ + b) * N_;
  #pragma unroll
  for (int r = 0; r < 2; ++r) {
    const int n = r * 256 + tid;
    float v = red[n] + red[512 + n] + red[1024 + n] + red[1536 + n];
    pb[n] = v;
  }
}

// ---------------- reducer: out = sum of 3 slabs + bias ----------------
__global__ __launch_bounds__(256)
void reduce_part(const float* __restrict__ part,
                 const float* __restrict__ Wb,
                 float* __restrict__ out) {
  const size_t S = (size_t)B_ * N_;
  int idx = (blockIdx.x * 256 + threadIdx.x) * 4;   // 256 blocks -> covers 262144
  f32x4 a0 = *(const f32x4u*)(part + idx);
  f32x4 a1 = *(const f32x4u*)(part + S + idx);
  f32x4 a2 = *(const f32x4u*)(part + 2 * S + idx);
  f32x4 wb = *(const f32x4u*)(Wb + (idx & (N_ - 1)));
  f32x4 r;
  #pragma unroll
  for (int i = 0; i < 4; ++i)
    r[i] = a0[i] + a1[i] + a2[i] + wb[i];
  *(f32x4*)(out + idx) = r;
}

// ---------------- R8 main kernel (ws fits wsf+wdf only; 110 us proven) ----------------
__global__ __launch_bounds__(256, 3)
void conv_fused_v8(const float* __restrict__ x,
                   const __bf16* __restrict__ wsf,
                   const float* __restrict__ wdf,
                   const float* __restrict__ Wb,
                   float* __restrict__ out) {
  __shared__ __align__(16) __bf16 Xs[CT * SXR];   // 51.2 KB
  __shared__ float red[4][64];                     // 1 KB

  const int tid  = threadIdx.x;
  const int id    = blockIdx.x;     // 0..1535
  const int slot  = id & 7;
  const int t8    = id >> 3;        // 0..191
  const int c_blk = t8 % 3;
  const int b     = (t8 / 3) * 8 + slot;

  const int lane  = tid & 63;
  const int wv    = tid >> 6;          // 4 waves: 2x2 (c,n) 64x64 quadrants
  const int cq    = (wv >> 1) * 64;
  const int nq    = (wv & 1) * 64;
  const int lrow  = lane & 15;
  const int lquad = lane >> 4;

  const float* src = x + ((size_t)b * C_ + (size_t)c_blk * CT) * HW_;
  #pragma unroll 4
  for (int p = 0; p < 24; ++p) {
    int i   = p * 256 + tid;
    int row = i / 48;
    int ch  = i - row * 48;
    const float* bp = src + row * HW_ + ch * 4;
    float v0 = 0.f, v1 = 0.f, v2 = 0.f, v3 = 0.f;
    if (ch < 42) {
      f32x4u t = *(const f32x4u*)bp;
      v0 = t[0]; v1 = t[1]; v2 = t[2]; v3 = t[3];
    } else if (ch == 42) {
      v0 = bp[0];
    }
    unsigned d0 = pack_trunc(v0, v1);
    unsigned d1 = pack_trunc(v2, v3);
    uint2 d; d.x = d0; d.y = d1;
    *(uint2*)&Xs[row * SXR + ch * 4] = d;
  }
  __syncthreads();

  const int cm0 = c_blk * 8 + (cq >> 4);

  #pragma unroll 1
  for (int nb = 0; nb < 4; ++nb) {
    const int nm0 = nb * 8 + (nq >> 4);
    const __bf16* bbase = wsf + ((size_t)nm0 * 6) * 512 + (size_t)lane * 8;

    const f32x4 zero = {0.f, 0.f, 0.f, 0.f};
    f32x4 acc[4][4];
    #pragma unroll
    for (int mi = 0; mi < 4; ++mi)
      #pragma unroll
      for (int ni = 0; ni < 4; ++ni)
        acc[mi][ni] = zero;

    #pragma unroll
    for (int kb = 0; kb < 6; ++kb) {
      bf16x8 afr[4], bfr[4];
      #pragma unroll
      for (int mi = 0; mi < 4; ++mi)
        afr[mi] = *(const bf16x8*)&Xs[(cq + mi * 16 + lrow) * SXR + kb * 32 + lquad * 8];
      #pragma unroll
      for (int ni = 0; ni < 4; ++ni)
        bfr[ni] = *(const bf16x8*)(bbase + ((size_t)ni * 6 + kb) * 512);
      #pragma unroll
      for (int mi = 0; mi < 4; ++mi)
        #pragma unroll
        for (int ni = 0; ni < 4; ++ni)
          acc[mi][ni] = __builtin_amdgcn_mfma_f32_16x16x32_bf16(
              afr[mi], bfr[ni], acc[mi][ni], 0, 0, 0);
    }

    float s[4] = {0.f, 0.f, 0.f, 0.f};
    #pragma unroll
    for (int ni = 0; ni < 4; ++ni) {
      #pragma unroll
      for (int mi = 0; mi < 4; ++mi) {
        const f32x4 w = *(const f32x4*)(wdf +
            (((size_t)(cm0 + mi) * 32 + (nm0 + ni)) * 64 + lane) * 4);
        s[ni] += acc[mi][ni][0] * w[0] + acc[mi][ni][1] * w[1]
               + acc[mi][ni][2] * w[2] + acc[mi][ni][3] * w[3];
      }
    }

    #pragma unroll
    for (int ni = 0; ni < 4; ++ni) {
      s[ni] += __shfl_xor(s[ni], 16, 64);
      s[ni] += __shfl_xor(s[ni], 32, 64);
    }
    if (lane < 16) {
      #pragma unroll
      for (int ni = 0; ni < 4; ++ni)
        red[wv][ni * 16 + lrow] = s[ni];
    }
    __syncthreads();

    if (tid < 128) {
      const int half = tid >> 6;
      const int idx  = tid & 63;
      const int n    = nb * 128 + tid;
      float v = red[half][idx] + red[half + 2][idx];
      if (c_blk == 0) v += Wb[n];
      atomicAdd(&out[(size_t)b * N_ + n], v);
    }
    __syncthreads();
  }
}

// ---------------- fallback main kernel (no workspace needed) ----------------

#define LDSS 104
#define KCH  96
#define NT   128

__global__ __launch_bounds__(256)
void conv_main_fallback(const float* __restrict__ x,
                        const float* __restrict__ Ws_g,
                        const float* __restrict__ Wd,
                        const float* __restrict__ Wb,
                        float* __restrict__ out) {
  __shared__ __align__(16) __bf16 Xs[CT][LDSS];
  __shared__ __align__(16) __bf16 Ws[NT][LDSS];

  const int tid   = threadIdx.x;
  const int n_blk = blockIdx.x;
  const int c_blk = blockIdx.y;
  const int b     = blockIdx.z;
  const int c0 = c_blk * CT;
  const int n0 = n_blk * NT;
  const int lane  = tid & 63;
  const int wv    = tid >> 6;
  const int cq    = (wv >> 1) * 64;
  const int nq    = (wv & 1) * 64;
  const int lrow  = lane & 15;
  const int lquad = lane >> 4;

  const f32x4 zero = {0.f, 0.f, 0.f, 0.f};
  f32x4 acc[4][4];
  #pragma unroll
  for (int mi = 0; mi < 4; ++mi)
    #pragma unroll
    for (int ni = 0; ni < 4; ++ni)
      acc[mi][ni] = zero;

  const float* xb  = x    + (size_t)b  * (C_ * HW_) + (size_t)c0 * HW_;
  const float* wsb = Ws_g + (size_t)n0 * HW_;

  for (int ch = 0; ch < 2; ++ch) {
    const int k0 = ch * KCH;
    __syncthreads();
    for (int e = tid; e < CT * KCH; e += 256) {
      int r   = e / KCH;
      int col = e - r * KCH;
      int k   = k0 + col;
      float vx = 0.f, vw = 0.f;
      if (k < HW_) {
        vx = xb [r * HW_ + k];
        vw = wsb[r * HW_ + k];
      }
      Xs[r][col] = f2bf(vx);
      Ws[r][col] = f2bf(vw);
    }
    __syncthreads();

    #pragma unroll
    for (int ks = 0; ks < 3; ++ks) {
      const int kc = ks * 32 + lquad * 8;
      bf16x8 afr[4], bfr[4];
      #pragma unroll
      for (int mi = 0; mi < 4; ++mi)
        afr[mi] = *(const bf16x8*)&Xs[cq + mi * 16 + lrow][kc];
      #pragma unroll
      for (int ni = 0; ni < 4; ++ni)
        bfr[ni] = *(const bf16x8*)&Ws[nq + ni * 16 + lrow][kc];
      #pragma unroll
      for (int mi = 0; mi < 4; ++mi)
        #pragma unroll
        for (int ni = 0; ni < 4; ++ni)
          acc[mi][ni] = __builtin_amdgcn_mfma_f32_16x16x32_bf16(
              afr[mi], bfr[ni], acc[mi][ni], 0, 0, 0);
    }
  }

  #pragma unroll
  for (int ni = 0; ni < 4; ++ni) {
    const int n = n0 + nq + ni * 16 + lrow;
    float sv = 0.f;
    #pragma unroll
    for (int mi = 0; mi < 4; ++mi) {
      const int cbase = c0 + cq + mi * 16 + lquad * 4;
      #pragma unroll
      for (int i = 0; i < 4; ++i)
        sv += acc[mi][ni][i] * Wd[(size_t)n * C_ + (cbase + i)];
    }
    sv += __shfl_xor(sv, 16, 64);
    sv += __shfl_xor(sv, 32, 64);
    if (lane < 16) {
      if (c_blk == 0 && cq == 0) sv += Wb[n];
      atomicAdd(&out[(size_t)b * N_ + n], sv);
    }
  }
}

extern "C" void kernel_launch(void* const* d_in, const int* in_sizes, int n_in,
                              void* d_out, int out_size, void* d_ws, size_t ws_size,
                              hipStream_t stream) {
  const float* x   = (const float*)d_in[0];   // [512,384,13,13]
  const float* Wsp = (const float*)d_in[1];   // [512,13,13]
  const float* Wd  = (const float*)d_in[2];   // [512,384]
  const float* Wb  = (const float*)d_in[3];   // [1,512]
  float* out = (float*)d_out;                 // [512,512] fp32

  const size_t need_basic = WSF_ELEMS * sizeof(__bf16) + WDF_ELEMS * sizeof(float);
  const size_t need_full  = need_basic + PART_ELEMS * sizeof(float);

  if (ws_size >= need_full) {
    __bf16* wsf  = (__bf16*)d_ws;
    float*  wdf  = (float*)(wsf + WSF_ELEMS);
    float*  partb = wdf + WDF_ELEMS;

    prep_aux_kernel<<<240, 256, 0, stream>>>(Wsp, Wd, wsf, wdf);
    conv_part<<<1536, 256, 0, stream>>>(x, wsf, wdf, partb);
    reduce_part<<<256, 256, 0, stream>>>(partb, Wb, out);
  } else if (ws_size >= need_basic) {
    __bf16* wsf = (__bf16*)d_ws;
    float*  wdf = (float*)(wsf + WSF_ELEMS);

    hipMemsetAsync(d_out, 0, (size_t)out_size * sizeof(float), stream);
    prep_aux_kernel<<<240, 256, 0, stream>>>(Wsp, Wd, wsf, wdf);
    conv_fused_v8<<<1536, 256, 0, stream>>>(x, wsf, wdf, Wb, out);
  } else {
    hipMemsetAsync(d_out, 0, (size_t)out_size * sizeof(float), stream);
    dim3 grid(N_ / NT, C_ / CT, B_);
    conv_main_fallback<<<grid, 256, 0, stream>>>(x, Wsp, Wd, Wb, out);
  }
}